// Round 3
// baseline (13658.096 us; speedup 1.0000x reference)
//
#include <hip/hip_runtime.h>
#include <stdint.h>

typedef unsigned short u16;
typedef __bf16 bf16x8 __attribute__((ext_vector_type(8)));
typedef float f32x4 __attribute__((ext_vector_type(4)));

#define DEV static __device__ __forceinline__

DEV u16 f2bu(float f) {
    union { float f; unsigned u; } v; v.f = f;
    unsigned r = v.u + 0x7FFFu + ((v.u >> 16) & 1u);
    return (u16)(r >> 16);
}
DEV float fast_tanh(float x) {
    float e = __expf(2.f * x);
    return 1.f - __fdividef(2.f, e + 1.f);
}
DEV float fast_sig(float x) {
    return __fdividef(1.f, 1.f + __expf(-x));
}
DEV void gload_lds(const u16* g, u16* l) {
    __builtin_amdgcn_global_load_lds((const __attribute__((address_space(1))) void*)g,
                                     (__attribute__((address_space(3))) void*)l, 16, 0, 0);
}

// ---------------------------------------------------------------------------
// Generic 128x128 MFMA GEMM (prologue GEMMs), BK=32, 4 waves (2x2).
// ---------------------------------------------------------------------------
template<bool A_F32, bool B_F32, bool B_KXN, bool OUT_BF16, bool BIAS>
__global__ __launch_bounds__(256) void gemm128(
    const void* __restrict__ Ap, int lda,
    const void* __restrict__ Bp, int ldb,
    void* __restrict__ Cp, int ldc,
    const float* __restrict__ bias, int K)
{
    __shared__ u16 As[128 * 40];
    __shared__ u16 Bs[128 * 40];
    const int tid = threadIdx.x;
    const int lane = tid & 63, wave = tid >> 6;
    const int wr = wave >> 1, wc = wave & 1;
    const int m0 = blockIdx.y * 128, n0 = blockIdx.x * 128;

    f32x4 acc[4][4];
#pragma unroll
    for (int m = 0; m < 4; ++m)
#pragma unroll
        for (int n = 0; n < 4; ++n)
            acc[m][n] = (f32x4){0.f, 0.f, 0.f, 0.f};

    for (int k0 = 0; k0 < K; k0 += 32) {
        __syncthreads();
        if (A_F32) {
            const float* A = (const float*)Ap;
#pragma unroll
            for (int i = 0; i < 4; ++i) {
                int c = tid + i * 256;
                int row = c >> 3, kc = (c & 7) * 4;
                float4 v = *(const float4*)&A[(size_t)(m0 + row) * lda + k0 + kc];
                ushort4 o; o.x = f2bu(v.x); o.y = f2bu(v.y); o.z = f2bu(v.z); o.w = f2bu(v.w);
                *(ushort4*)&As[row * 40 + kc] = o;
            }
        } else {
            const u16* A = (const u16*)Ap;
#pragma unroll
            for (int i = 0; i < 2; ++i) {
                int c = tid + i * 256;
                int row = c >> 2, kc = (c & 3) * 8;
                *(int4*)&As[row * 40 + kc] = *(const int4*)&A[(size_t)(m0 + row) * lda + k0 + kc];
            }
        }
        if (B_KXN) {
            const float* B = (const float*)Bp;
#pragma unroll
            for (int i = 0; i < 4; ++i) {
                int c = tid + i * 256;
                int kk = c >> 5, nc = (c & 31) * 4;
                float4 v = *(const float4*)&B[(size_t)(k0 + kk) * ldb + n0 + nc];
                Bs[(nc + 0) * 40 + kk] = f2bu(v.x);
                Bs[(nc + 1) * 40 + kk] = f2bu(v.y);
                Bs[(nc + 2) * 40 + kk] = f2bu(v.z);
                Bs[(nc + 3) * 40 + kk] = f2bu(v.w);
            }
        } else if (B_F32) {
            const float* B = (const float*)Bp;
#pragma unroll
            for (int i = 0; i < 4; ++i) {
                int c = tid + i * 256;
                int row = c >> 3, kc = (c & 7) * 4;
                float4 v = *(const float4*)&B[(size_t)(n0 + row) * ldb + k0 + kc];
                ushort4 o; o.x = f2bu(v.x); o.y = f2bu(v.y); o.z = f2bu(v.z); o.w = f2bu(v.w);
                *(ushort4*)&Bs[row * 40 + kc] = o;
            }
        } else {
            const u16* B = (const u16*)Bp;
#pragma unroll
            for (int i = 0; i < 2; ++i) {
                int c = tid + i * 256;
                int row = c >> 2, kc = (c & 3) * 8;
                *(int4*)&Bs[row * 40 + kc] = *(const int4*)&B[(size_t)(n0 + row) * ldb + k0 + kc];
            }
        }
        __syncthreads();
        const int fr = lane & 15, kq = (lane >> 4) * 8;
        bf16x8 af[4], bq[4];
#pragma unroll
        for (int m = 0; m < 4; ++m)
            af[m] = *(const bf16x8*)&As[(wr * 64 + m * 16 + fr) * 40 + kq];
#pragma unroll
        for (int n = 0; n < 4; ++n)
            bq[n] = *(const bf16x8*)&Bs[(wc * 64 + n * 16 + fr) * 40 + kq];
#pragma unroll
        for (int m = 0; m < 4; ++m)
#pragma unroll
            for (int n = 0; n < 4; ++n)
                acc[m][n] = __builtin_amdgcn_mfma_f32_16x16x32_bf16(af[m], bq[n], acc[m][n], 0, 0, 0);
    }
    const int fr = lane & 15, rq = (lane >> 4) * 4;
#pragma unroll
    for (int m = 0; m < 4; ++m) {
#pragma unroll
        for (int n = 0; n < 4; ++n) {
            int col = n0 + wc * 64 + n * 16 + fr;
            float bv = BIAS ? bias[col] : 0.f;
#pragma unroll
            for (int r = 0; r < 4; ++r) {
                int row = m0 + wr * 64 + m * 16 + rq + r;
                float v = acc[m][n][r] + bv;
                if (OUT_BF16) ((u16*)Cp)[(size_t)row * ldc + col] = f2bu(v);
                else          ((float*)Cp)[(size_t)row * ldc + col] = v;
            }
        }
    }
}

// ---------------------------------------------------------------------------
// Head GEMM: C[2048][32000] = A(bf16 [2048][1024]) @ B(bf16 [32000][1024])^T
// ---------------------------------------------------------------------------
__global__ __launch_bounds__(256) void gemm_head(const u16* __restrict__ A,
                                                 const u16* __restrict__ B,
                                                 float* __restrict__ C)
{
    __shared__ u16 As[128 * 32];
    __shared__ u16 Bs[128 * 32];
    const int tid = threadIdx.x, lane = tid & 63, wave = tid >> 6;
    const int wr = wave >> 1, wc = wave & 1;
    int bid = blockIdx.x;                       // 4000 = 8 * 500
    int nb = (bid & 7) * 500 + (bid >> 3);      // XCD-chunked
    const int m0 = (nb & 15) * 128;             // m fastest -> B-panel L2 reuse
    const int n0 = (nb >> 4) * 128;

    f32x4 acc[4][4];
#pragma unroll
    for (int m = 0; m < 4; ++m)
#pragma unroll
        for (int n = 0; n < 4; ++n)
            acc[m][n] = (f32x4){0.f, 0.f, 0.f, 0.f};

    const int srow = lane >> 2;
    const int sk = (lane & 3) * 8;
    const int fr = lane & 15, kq = (lane >> 4) * 8;

    for (int k0 = 0; k0 < 1024; k0 += 32) {
        __syncthreads();
#pragma unroll
        for (int j = 0; j < 2; ++j) {
            const int rb = (j * 4 + wave) * 16;
            gload_lds(&A[(size_t)(m0 + rb + srow) * 1024 + k0 + sk], &As[rb * 32]);
            gload_lds(&B[(size_t)(n0 + rb + srow) * 1024 + k0 + sk], &Bs[rb * 32]);
        }
        __syncthreads();
        bf16x8 af[4], bq[4];
#pragma unroll
        for (int m = 0; m < 4; ++m)
            af[m] = *(const bf16x8*)&As[(wr * 64 + m * 16 + fr) * 32 + kq];
#pragma unroll
        for (int n = 0; n < 4; ++n)
            bq[n] = *(const bf16x8*)&Bs[(wc * 64 + n * 16 + fr) * 32 + kq];
#pragma unroll
        for (int m = 0; m < 4; ++m)
#pragma unroll
            for (int n = 0; n < 4; ++n)
                acc[m][n] = __builtin_amdgcn_mfma_f32_16x16x32_bf16(af[m], bq[n], acc[m][n], 0, 0, 0);
    }
    const int rq = (lane >> 4) * 4;
#pragma unroll
    for (int m = 0; m < 4; ++m)
#pragma unroll
        for (int n = 0; n < 4; ++n) {
            int col = n0 + wc * 64 + n * 16 + fr;
#pragma unroll
            for (int r = 0; r < 4; ++r)
                C[(size_t)(m0 + wr * 64 + m * 16 + rq + r) * 32000 + col] = acc[m][n][r];
        }
}

// ---------------------------------------------------------------------------
// Prologue kernels
// ---------------------------------------------------------------------------
__global__ __launch_bounds__(256) void mean_k(const float* __restrict__ img, float* __restrict__ gT)
{
    int b = blockIdx.x >> 3, ch = blockIdx.x & 7;
    int d = ch * 256 + threadIdx.x;
    float s = 0.f;
    for (int n = 0; n < 196; ++n)
        s += img[((size_t)b * 196 + n) * 2048 + d];
    gT[d * 64 + b] = s * (1.f / 196.f);
}

__global__ __launch_bounds__(256) void emb_gather(const int* __restrict__ tok,
                                                  const float* __restrict__ embed,
                                                  u16* __restrict__ emb_bf)
{
    int id = blockIdx.x * 256 + threadIdx.x;
    int row = id >> 9, e = id & 511;
    int tk = tok[row];
    emb_bf[(size_t)row * 512 + e] = f2bu(embed[(size_t)tk * 512 + e]);
}

__global__ __launch_bounds__(256) void cvt_bf16(const float* __restrict__ in, u16* __restrict__ out)
{
    int i = blockIdx.x * 256 + threadIdx.x;
    float4 v = ((const float4*)in)[i];
    ushort4 o; o.x = f2bu(v.x); o.y = f2bu(v.y); o.z = f2bu(v.z); o.w = f2bu(v.w);
    ((ushort4*)out)[i] = o;
}

__global__ __launch_bounds__(256) void bias_sum(const float* __restrict__ a, const float* __restrict__ b,
                                                float* __restrict__ o)
{
    int i = blockIdx.x * 256 + threadIdx.x;
    o[i] = a[i] + b[i];
}

__global__ __launch_bounds__(256) void h0c0(const float* __restrict__ gT,
                                            const float* __restrict__ Wh0, const float* __restrict__ bh0,
                                            const float* __restrict__ Wc0, const float* __restrict__ bc0,
                                            float* __restrict__ c, u16* __restrict__ h0)
{
    int id = blockIdx.x * 256 + threadIdx.x;
    int b = id & 63, n = id >> 6;
    const float4* Wh = (const float4*)&Wh0[(size_t)n * 2048];
    const float4* Wc = (const float4*)&Wc0[(size_t)n * 2048];
    float s0 = 0.f, s1 = 0.f;
#pragma unroll 4
    for (int k4 = 0; k4 < 512; ++k4) {
        float4 wh = Wh[k4], wc = Wc[k4];
        float g0 = gT[(k4 * 4 + 0) * 64 + b];
        float g1 = gT[(k4 * 4 + 1) * 64 + b];
        float g2 = gT[(k4 * 4 + 2) * 64 + b];
        float g3 = gT[(k4 * 4 + 3) * 64 + b];
        s0 += wh.x * g0 + wh.y * g1 + wh.z * g2 + wh.w * g3;
        s1 += wc.x * g0 + wc.y * g1 + wc.z * g2 + wc.w * g3;
    }
    c[b * 1024 + n] = fast_tanh(s1 + bc0[n]);
    h0[(size_t)b * 1024 + n] = f2bu(fast_tanh(s0 + bh0[n]));
}

// ---------------------------------------------------------------------------
// Flag-array grid barrier: arrival = release-store to private slot (128B
// spaced); master block (255, idle in P1/P3) polls all slots with one wave,
// then release-stores epoch to `rel`; others poll `rel` only.
// ---------------------------------------------------------------------------
DEV void gbar(unsigned* slots, unsigned* rel, int bid, unsigned ep)
{
    __syncthreads();
    if (threadIdx.x < 64) {
        if (threadIdx.x == 0)
            __hip_atomic_store(&slots[bid * 32], ep, __ATOMIC_RELEASE, __HIP_MEMORY_SCOPE_AGENT);
        if (bid == 255) {
            unsigned long long t0 = __builtin_amdgcn_s_memrealtime();
            for (;;) {
                bool ok = true;
#pragma unroll
                for (int i = 0; i < 4; ++i) {
                    unsigned v = __hip_atomic_load(&slots[(threadIdx.x * 4 + i) * 32],
                                                   __ATOMIC_ACQUIRE, __HIP_MEMORY_SCOPE_AGENT);
                    ok = ok && (v >= ep);
                }
                if (__all(ok)) break;
                __builtin_amdgcn_s_sleep(4);
                if (__builtin_amdgcn_s_memrealtime() - t0 > 10000000ULL) break;  // ~100ms escape
            }
            if (threadIdx.x == 0)
                __hip_atomic_store(rel, ep, __ATOMIC_RELEASE, __HIP_MEMORY_SCOPE_AGENT);
        } else if (threadIdx.x == 0) {
            unsigned long long t0 = __builtin_amdgcn_s_memrealtime();
            while (__hip_atomic_load(rel, __ATOMIC_ACQUIRE, __HIP_MEMORY_SCOPE_AGENT) < ep) {
                __builtin_amdgcn_s_sleep(4);
                if (__builtin_amdgcn_s_memrealtime() - t0 > 10000000ULL) break;
            }
        }
    }
    __syncthreads();
}

// ---------------------------------------------------------------------------
// Persistent recurrence: 256 blocks x 256 threads, 32 steps, 3 barriers/step.
// P1 (blocks 0..63):  ph + scores + softmax -> probs   (per-batch)
// P2 (all 256):       ctx quarters -> ctx_bf
// P3 (blocks 0..63):  gates MFMA (M=64,N=64,K=3072) + LSTM pointwise
// ---------------------------------------------------------------------------
__global__ __launch_bounds__(256, 2) void recur(
    const u16* __restrict__ Whid_bf,   // [256][1024]
    const u16* __restrict__ Wic,       // [4096][2048]
    const u16* __restrict__ Whh_bf,    // [4096][1024]
    const float* __restrict__ proj,    // [64][196][256]
    const u16* __restrict__ img_bf,    // [64][196][2048]
    const float* __restrict__ w_score, // [256]
    const float* __restrict__ xg,      // [2048][4096]
    float* __restrict__ cbuf,          // [64][1024]
    u16* __restrict__ hbuf,            // [2][64][1024]
    u16* __restrict__ ctx_bf,          // [64][2048]
    float* __restrict__ probs,         // [64][200]
    u16* __restrict__ h_all,           // [2048][1024]
    unsigned* __restrict__ slots,      // [256*32]
    unsigned* __restrict__ rel)
{
    const int bid = blockIdx.x, tid = threadIdx.x;
    const int lane = tid & 63, wave = tid >> 6;
    const int fr = lane & 15, kq = (lane >> 4) * 8, rq = (lane >> 4) * 4;
    __shared__ union {
        struct { float ph[256], ws[256], sc[256], red[256]; } p1;
        struct { float sc[200]; float part[4][512]; } p2;
        float dred[4][64][64];
    } sm;
    unsigned ep = 0;

    for (int t = 0; t < 32; ++t) {
        const int cur = t & 1, nxt = cur ^ 1;
        const u16* hb = hbuf + cur * 65536;

        // ---- P1: ph + scores + softmax (per-batch block)
        if (bid < 64) {
            const int b = bid;
            sm.p1.ws[tid] = w_score[tid];
            sm.p1.sc[tid] = -1e30f;
            // h slice for this lane (16 elems)
            float hv[16];
            {
                const u16* hrow = hb + b * 1024 + lane * 16;
                bf16x8 h0 = *(const bf16x8*)hrow;
                bf16x8 h1 = *(const bf16x8*)(hrow + 8);
#pragma unroll
                for (int i = 0; i < 8; ++i) { hv[i] = (float)h0[i]; hv[8 + i] = (float)h1[i]; }
            }
            // ph[col] = dot(h, Whid[col]); wave w covers cols w*64..w*64+63
            for (int c = 0; c < 64; ++c) {
                const int col = wave * 64 + c;
                const u16* wrow = Whid_bf + (size_t)col * 1024 + lane * 16;
                bf16x8 w0 = *(const bf16x8*)wrow;
                bf16x8 w1 = *(const bf16x8*)(wrow + 8);
                float s = 0.f;
#pragma unroll
                for (int i = 0; i < 8; ++i) s += hv[i] * (float)w0[i] + hv[8 + i] * (float)w1[i];
#pragma unroll
                for (int off = 32; off; off >>= 1) s += __shfl_xor(s, off, 64);
                if (lane == 0) sm.p1.ph[col] = s;
            }
            __syncthreads();
            // scores
            for (int n = wave; n < 196; n += 4) {
                const int a0 = lane * 4;
                float4 p = *(const float4*)&proj[((size_t)b * 196 + n) * 256 + a0];
                float s = sm.p1.ws[a0 + 0] * fast_tanh(p.x + sm.p1.ph[a0 + 0])
                        + sm.p1.ws[a0 + 1] * fast_tanh(p.y + sm.p1.ph[a0 + 1])
                        + sm.p1.ws[a0 + 2] * fast_tanh(p.z + sm.p1.ph[a0 + 2])
                        + sm.p1.ws[a0 + 3] * fast_tanh(p.w + sm.p1.ph[a0 + 3]);
#pragma unroll
                for (int off = 32; off; off >>= 1) s += __shfl_xor(s, off, 64);
                if (lane == 0) sm.p1.sc[n] = s;
            }
            __syncthreads();
            // softmax over 196
            sm.p1.red[tid] = sm.p1.sc[tid];
            __syncthreads();
#pragma unroll
            for (int s2 = 128; s2 > 0; s2 >>= 1) {
                if (tid < s2) sm.p1.red[tid] = fmaxf(sm.p1.red[tid], sm.p1.red[tid + s2]);
                __syncthreads();
            }
            const float mx = sm.p1.red[0];
            __syncthreads();
            float e = (tid < 196) ? __expf(sm.p1.sc[tid] - mx) : 0.f;
            sm.p1.red[tid] = e;
            __syncthreads();
#pragma unroll
            for (int s2 = 128; s2 > 0; s2 >>= 1) {
                if (tid < s2) sm.p1.red[tid] += sm.p1.red[tid + s2];
                __syncthreads();
            }
            if (tid < 196) probs[b * 200 + tid] = e * __fdividef(1.f, sm.p1.red[0]);
        }
        gbar(slots, rel, bid, ++ep);

        // ---- P2: ctx (all 256 blocks: b = bid>>2, quarter q = bid&3)
        {
            const int b = bid >> 2, q = bid & 3;
            if (tid < 196) sm.p2.sc[tid] = probs[b * 200 + tid];
            __syncthreads();
            const int gid = tid >> 2, st = tid & 3;
            const int c0 = q * 512 + gid * 8;
            const u16* base = img_bf + ((size_t)b * 196) * 2048 + c0;
            float a[8];
#pragma unroll
            for (int i = 0; i < 8; ++i) a[i] = 0.f;
            for (int n = st; n < 196; n += 4) {
                bf16x8 v = *(const bf16x8*)(base + (size_t)n * 2048);
                float w = sm.p2.sc[n];
#pragma unroll
                for (int i = 0; i < 8; ++i) a[i] += w * (float)v[i];
            }
#pragma unroll
            for (int i = 0; i < 8; ++i) sm.p2.part[st][gid * 8 + i] = a[i];
            __syncthreads();
            const int col = tid * 2;
            float v0 = sm.p2.part[0][col] + sm.p2.part[1][col] + sm.p2.part[2][col] + sm.p2.part[3][col];
            float v1 = sm.p2.part[0][col + 1] + sm.p2.part[1][col + 1] + sm.p2.part[2][col + 1] + sm.p2.part[3][col + 1];
            ushort2 o; o.x = f2bu(v0); o.y = f2bu(v1);
            *(ushort2*)&ctx_bf[(size_t)b * 2048 + q * 512 + col] = o;
        }
        gbar(slots, rel, bid, ++ep);

        // ---- P3: gates (blocks 0..63, 16 h-cols x 4 gates = 64 gate-rows each)
        if (bid < 64) {
            const int hc0 = bid * 16;
            f32x4 dacc[4][4];  // [m-tile][gate]
#pragma unroll
            for (int m = 0; m < 4; ++m)
#pragma unroll
                for (int g = 0; g < 4; ++g)
                    dacc[m][g] = (f32x4){0.f, 0.f, 0.f, 0.f};
            for (int kk = 0; kk < 768; kk += 32) {
                const int k0 = wave * 768 + kk;
                bf16x8 af[4];
                if (k0 < 2048) {
#pragma unroll
                    for (int m = 0; m < 4; ++m)
                        af[m] = *(const bf16x8*)&ctx_bf[(size_t)(m * 16 + fr) * 2048 + k0 + kq];
#pragma unroll
                    for (int g = 0; g < 4; ++g) {
                        bf16x8 bq = *(const bf16x8*)&Wic[(size_t)(g * 1024 + hc0 + fr) * 2048 + k0 + kq];
#pragma unroll
                        for (int m = 0; m < 4; ++m)
                            dacc[m][g] = __builtin_amdgcn_mfma_f32_16x16x32_bf16(af[m], bq, dacc[m][g], 0, 0, 0);
                    }
                } else {
                    const int kh = k0 - 2048;
#pragma unroll
                    for (int m = 0; m < 4; ++m)
                        af[m] = *(const bf16x8*)&hb[(size_t)(m * 16 + fr) * 1024 + kh + kq];
#pragma unroll
                    for (int g = 0; g < 4; ++g) {
                        bf16x8 bq = *(const bf16x8*)&Whh_bf[(size_t)(g * 1024 + hc0 + fr) * 1024 + kh + kq];
#pragma unroll
                        for (int m = 0; m < 4; ++m)
                            dacc[m][g] = __builtin_amdgcn_mfma_f32_16x16x32_bf16(af[m], bq, dacc[m][g], 0, 0, 0);
                    }
                }
            }
            __syncthreads();
#pragma unroll
            for (int m = 0; m < 4; ++m)
#pragma unroll
                for (int g = 0; g < 4; ++g)
#pragma unroll
                    for (int r = 0; r < 4; ++r)
                        sm.dred[wave][m * 16 + rq + r][g * 16 + fr] = dacc[m][g][r];
            __syncthreads();
            // pointwise: 64 b x 16 cols = 1024 items
#pragma unroll
            for (int i = 0; i < 4; ++i) {
                const int idx = tid + i * 256;
                const int bb = idx >> 4, j = idx & 15;
                const int col = hc0 + j;
                float G[4];
#pragma unroll
                for (int g = 0; g < 4; ++g) {
                    const int f2 = g * 16 + j;
                    G[g] = sm.dred[0][bb][f2] + sm.dred[1][bb][f2] + sm.dred[2][bb][f2] + sm.dred[3][bb][f2]
                         + xg[((size_t)bb * 32 + t) * 4096 + g * 1024 + col];
                }
                float ig = fast_sig(G[0]), fg = fast_sig(G[1]);
                float gv = fast_tanh(G[2]), og = fast_sig(G[3]);
                float cp = cbuf[bb * 1024 + col];
                float cn = fg * cp + ig * gv;
                cbuf[bb * 1024 + col] = cn;
                u16 hv = f2bu(og * fast_tanh(cn));
                hbuf[nxt * 65536 + bb * 1024 + col] = hv;
                h_all[((size_t)bb * 32 + t) * 1024 + col] = hv;
            }
        }
        gbar(slots, rel, bid, ++ep);
    }
}

// ---------------------------------------------------------------------------
extern "C" void kernel_launch(void* const* d_in, const int* in_sizes, int n_in,
                              void* d_out, int out_size, void* d_ws, size_t ws_size,
                              hipStream_t stream)
{
    const float* img     = (const float*)d_in[0];
    const int*   tok     = (const int*)d_in[1];
    const float* embed   = (const float*)d_in[2];
    const float* W_head1 = (const float*)d_in[3];
    const float* W_ih    = (const float*)d_in[4];
    const float* W_hh    = (const float*)d_in[5];
    const float* b_ih    = (const float*)d_in[6];
    const float* b_hh    = (const float*)d_in[7];
    const float* W_head  = (const float*)d_in[8];
    const float* W_img   = (const float*)d_in[9];
    const float* W_hid   = (const float*)d_in[10];
    const float* w_score = (const float*)d_in[11];
    const float* W_h0    = (const float*)d_in[12];
    const float* b_h0    = (const float*)d_in[13];
    const float* W_c0    = (const float*)d_in[14];
    const float* b_c0    = (const float*)d_in[15];
    float* out = (float*)d_out;

    char* w = (char*)d_ws;
    size_t off = 0;
    auto alloc = [&](size_t bytes) { char* p = w + off; off += (bytes + 255) & ~(size_t)255; return p; };

    u16*   Wic      = (u16*)alloc(4096ULL * 2048 * 2);
    u16*   Whh_bf   = (u16*)alloc(4096ULL * 1024 * 2);
    u16*   Whid_bf  = (u16*)alloc(256ULL * 1024 * 2);
    u16*   Whead_bf = (u16*)alloc(32000ULL * 1024 * 2);
    u16*   img_bf   = (u16*)alloc(64ULL * 196 * 2048 * 2);
    float* xg       = (float*)alloc(2048ULL * 4096 * 4);
    float* proj     = (float*)alloc(64ULL * 196 * 256 * 4);
    u16*   emb_bf   = (u16*)alloc(2048ULL * 512 * 2);
    u16*   xe       = (u16*)alloc(2048ULL * 512 * 2);
    float* gT       = (float*)alloc(2048ULL * 64 * 4);
    float* cbuf     = (float*)alloc(64ULL * 1024 * 4);
    u16*   hbuf     = (u16*)alloc(2ULL * 64 * 1024 * 2);
    u16*   ctx_bf   = (u16*)alloc(64ULL * 2048 * 2);
    u16*   h_all    = (u16*)alloc(2048ULL * 1024 * 2);
    float* probs    = (float*)alloc(64ULL * 200 * 4);
    float* bsum     = (float*)alloc(4096ULL * 4);
    unsigned* slots = (unsigned*)alloc(256 * 32 * 4 + 256);  // 128B-spaced slots + rel line
    unsigned* rel   = slots + 256 * 32;
    (void)ws_size; (void)in_sizes; (void)n_in; (void)out_size;

    // ---- prologue
    mean_k<<<dim3(512), dim3(256), 0, stream>>>(img, gT);
    emb_gather<<<dim3(4096), dim3(256), 0, stream>>>(tok, embed, emb_bf);
    cvt_bf16<<<dim3(4096), dim3(256), 0, stream>>>(W_hh, Whh_bf);
    cvt_bf16<<<dim3(256), dim3(256), 0, stream>>>(W_hid, Whid_bf);
    cvt_bf16<<<dim3(32000), dim3(256), 0, stream>>>(W_head, Whead_bf);
    cvt_bf16<<<dim3(25088), dim3(256), 0, stream>>>(img, img_bf);
    bias_sum<<<dim3(16), dim3(256), 0, stream>>>(b_ih, b_hh, bsum);
    h0c0<<<dim3(256), dim3(256), 0, stream>>>(gT, W_h0, b_h0, W_c0, b_c0, cbuf, hbuf);

    gemm128<false, true, false, true, false><<<dim3(4, 16), dim3(256), 0, stream>>>(
        emb_bf, 512, W_head1, 2560, xe, 512, nullptr, 512);
    gemm128<false, true, false, false, true><<<dim3(32, 16), dim3(256), 0, stream>>>(
        xe, 512, W_ih, 512, xg, 4096, bsum, 512);
    gemm128<true, true, true, true, false><<<dim3(16, 32), dim3(256), 0, stream>>>(
        W_ih, 512, W_head1 + 512, 2560, Wic, 2048, nullptr, 512);
    gemm128<true, true, false, false, false><<<dim3(2, 98), dim3(256), 0, stream>>>(
        img, 2048, W_img, 2048, proj, 256, nullptr, 2048);

    // ---- recurrence (persistent, flag-array barrier, 96 epochs)
    hipMemsetAsync(slots, 0, 256 * 32 * 4 + 256, stream);
    recur<<<dim3(256), dim3(256), 0, stream>>>(Whid_bf, Wic, Whh_bf, proj, img_bf,
                                               w_score, xg, cbuf, hbuf, ctx_bf,
                                               probs, h_all, slots, rel);

    // ---- logits: out = h_all @ W_head^T
    gemm_head<<<dim3(4000), dim3(256), 0, stream>>>(h_all, Whead_bf, out);
}

// Round 4
// 3034.295 us; speedup vs baseline: 4.5012x; 4.5012x over previous
//
#include <hip/hip_runtime.h>
#include <stdint.h>

typedef unsigned short u16;
typedef __bf16 bf16x8 __attribute__((ext_vector_type(8)));
typedef float f32x4 __attribute__((ext_vector_type(4)));

#define DEV static __device__ __forceinline__

DEV u16 f2bu(float f) {
    union { float f; unsigned u; } v; v.f = f;
    unsigned r = v.u + 0x7FFFu + ((v.u >> 16) & 1u);
    return (u16)(r >> 16);
}
DEV float b2f(u16 b) {
    union { unsigned u; float f; } v; v.u = ((unsigned)b) << 16;
    return v.f;
}
DEV float fast_tanh(float x) {
    float e = __expf(2.f * x);
    return 1.f - __fdividef(2.f, e + 1.f);
}
DEV float fast_sig(float x) {
    return __fdividef(1.f, 1.f + __expf(-x));
}
DEV void gload_lds(const u16* g, u16* l) {
    __builtin_amdgcn_global_load_lds((const __attribute__((address_space(1))) void*)g,
                                     (__attribute__((address_space(3))) void*)l, 16, 0, 0);
}

// ---------------------------------------------------------------------------
// Generic 128x128 MFMA GEMM (prologue GEMMs), BK=32, 4 waves (2x2).
// ---------------------------------------------------------------------------
template<bool A_F32, bool B_F32, bool B_KXN, bool OUT_BF16, bool BIAS>
__global__ __launch_bounds__(256) void gemm128(
    const void* __restrict__ Ap, int lda,
    const void* __restrict__ Bp, int ldb,
    void* __restrict__ Cp, int ldc,
    const float* __restrict__ bias, int K)
{
    __shared__ u16 As[128 * 40];
    __shared__ u16 Bs[128 * 40];
    const int tid = threadIdx.x;
    const int lane = tid & 63, wave = tid >> 6;
    const int wr = wave >> 1, wc = wave & 1;
    const int m0 = blockIdx.y * 128, n0 = blockIdx.x * 128;

    f32x4 acc[4][4];
#pragma unroll
    for (int m = 0; m < 4; ++m)
#pragma unroll
        for (int n = 0; n < 4; ++n)
            acc[m][n] = (f32x4){0.f, 0.f, 0.f, 0.f};

    for (int k0 = 0; k0 < K; k0 += 32) {
        __syncthreads();
        if (A_F32) {
            const float* A = (const float*)Ap;
#pragma unroll
            for (int i = 0; i < 4; ++i) {
                int c = tid + i * 256;
                int row = c >> 3, kc = (c & 7) * 4;
                float4 v = *(const float4*)&A[(size_t)(m0 + row) * lda + k0 + kc];
                ushort4 o; o.x = f2bu(v.x); o.y = f2bu(v.y); o.z = f2bu(v.z); o.w = f2bu(v.w);
                *(ushort4*)&As[row * 40 + kc] = o;
            }
        } else {
            const u16* A = (const u16*)Ap;
#pragma unroll
            for (int i = 0; i < 2; ++i) {
                int c = tid + i * 256;
                int row = c >> 2, kc = (c & 3) * 8;
                *(int4*)&As[row * 40 + kc] = *(const int4*)&A[(size_t)(m0 + row) * lda + k0 + kc];
            }
        }
        if (B_KXN) {
            const float* B = (const float*)Bp;
#pragma unroll
            for (int i = 0; i < 4; ++i) {
                int c = tid + i * 256;
                int kk = c >> 5, nc = (c & 31) * 4;
                float4 v = *(const float4*)&B[(size_t)(k0 + kk) * ldb + n0 + nc];
                Bs[(nc + 0) * 40 + kk] = f2bu(v.x);
                Bs[(nc + 1) * 40 + kk] = f2bu(v.y);
                Bs[(nc + 2) * 40 + kk] = f2bu(v.z);
                Bs[(nc + 3) * 40 + kk] = f2bu(v.w);
            }
        } else if (B_F32) {
            const float* B = (const float*)Bp;
#pragma unroll
            for (int i = 0; i < 4; ++i) {
                int c = tid + i * 256;
                int row = c >> 3, kc = (c & 7) * 4;
                float4 v = *(const float4*)&B[(size_t)(n0 + row) * ldb + k0 + kc];
                ushort4 o; o.x = f2bu(v.x); o.y = f2bu(v.y); o.z = f2bu(v.z); o.w = f2bu(v.w);
                *(ushort4*)&Bs[row * 40 + kc] = o;
            }
        } else {
            const u16* B = (const u16*)Bp;
#pragma unroll
            for (int i = 0; i < 2; ++i) {
                int c = tid + i * 256;
                int row = c >> 2, kc = (c & 3) * 8;
                *(int4*)&Bs[row * 40 + kc] = *(const int4*)&B[(size_t)(n0 + row) * ldb + k0 + kc];
            }
        }
        __syncthreads();
        const int fr = lane & 15, kq = (lane >> 4) * 8;
        bf16x8 af[4], bq[4];
#pragma unroll
        for (int m = 0; m < 4; ++m)
            af[m] = *(const bf16x8*)&As[(wr * 64 + m * 16 + fr) * 40 + kq];
#pragma unroll
        for (int n = 0; n < 4; ++n)
            bq[n] = *(const bf16x8*)&Bs[(wc * 64 + n * 16 + fr) * 40 + kq];
#pragma unroll
        for (int m = 0; m < 4; ++m)
#pragma unroll
            for (int n = 0; n < 4; ++n)
                acc[m][n] = __builtin_amdgcn_mfma_f32_16x16x32_bf16(af[m], bq[n], acc[m][n], 0, 0, 0);
    }
    const int fr = lane & 15, rq = (lane >> 4) * 4;
#pragma unroll
    for (int m = 0; m < 4; ++m) {
#pragma unroll
        for (int n = 0; n < 4; ++n) {
            int col = n0 + wc * 64 + n * 16 + fr;
            float bv = BIAS ? bias[col] : 0.f;
#pragma unroll
            for (int r = 0; r < 4; ++r) {
                int row = m0 + wr * 64 + m * 16 + rq + r;
                float v = acc[m][n][r] + bv;
                if (OUT_BF16) ((u16*)Cp)[(size_t)row * ldc + col] = f2bu(v);
                else          ((float*)Cp)[(size_t)row * ldc + col] = v;
            }
        }
    }
}

// ---------------------------------------------------------------------------
// Head GEMM: C[2048][32000] = A(bf16 [2048][1024]) @ B(bf16 [32000][1024])^T
// ---------------------------------------------------------------------------
__global__ __launch_bounds__(256) void gemm_head(const u16* __restrict__ A,
                                                 const u16* __restrict__ B,
                                                 float* __restrict__ C)
{
    __shared__ u16 As[128 * 32];
    __shared__ u16 Bs[128 * 32];
    const int tid = threadIdx.x, lane = tid & 63, wave = tid >> 6;
    const int wr = wave >> 1, wc = wave & 1;
    int bid = blockIdx.x;                       // 4000 = 8 * 500
    int nb = (bid & 7) * 500 + (bid >> 3);      // XCD-chunked
    const int m0 = (nb & 15) * 128;             // m fastest -> B-panel L2 reuse
    const int n0 = (nb >> 4) * 128;

    f32x4 acc[4][4];
#pragma unroll
    for (int m = 0; m < 4; ++m)
#pragma unroll
        for (int n = 0; n < 4; ++n)
            acc[m][n] = (f32x4){0.f, 0.f, 0.f, 0.f};

    const int srow = lane >> 2;
    const int sk = (lane & 3) * 8;
    const int fr = lane & 15, kq = (lane >> 4) * 8;

    for (int k0 = 0; k0 < 1024; k0 += 32) {
        __syncthreads();
#pragma unroll
        for (int j = 0; j < 2; ++j) {
            const int rb = (j * 4 + wave) * 16;
            gload_lds(&A[(size_t)(m0 + rb + srow) * 1024 + k0 + sk], &As[rb * 32]);
            gload_lds(&B[(size_t)(n0 + rb + srow) * 1024 + k0 + sk], &Bs[rb * 32]);
        }
        __syncthreads();
        bf16x8 af[4], bq[4];
#pragma unroll
        for (int m = 0; m < 4; ++m)
            af[m] = *(const bf16x8*)&As[(wr * 64 + m * 16 + fr) * 32 + kq];
#pragma unroll
        for (int n = 0; n < 4; ++n)
            bq[n] = *(const bf16x8*)&Bs[(wc * 64 + n * 16 + fr) * 32 + kq];
#pragma unroll
        for (int m = 0; m < 4; ++m)
#pragma unroll
            for (int n = 0; n < 4; ++n)
                acc[m][n] = __builtin_amdgcn_mfma_f32_16x16x32_bf16(af[m], bq[n], acc[m][n], 0, 0, 0);
    }
    const int rq = (lane >> 4) * 4;
#pragma unroll
    for (int m = 0; m < 4; ++m)
#pragma unroll
        for (int n = 0; n < 4; ++n) {
            int col = n0 + wc * 64 + n * 16 + fr;
#pragma unroll
            for (int r = 0; r < 4; ++r)
                C[(size_t)(m0 + wr * 64 + m * 16 + rq + r) * 32000 + col] = acc[m][n][r];
        }
}

// ---------------------------------------------------------------------------
// Prologue kernels
// ---------------------------------------------------------------------------
__global__ __launch_bounds__(256) void cvt_bf16(const float* __restrict__ in, u16* __restrict__ out)
{
    int i = blockIdx.x * 256 + threadIdx.x;
    float4 v = ((const float4*)in)[i];
    ushort4 o; o.x = f2bu(v.x); o.y = f2bu(v.y); o.z = f2bu(v.z); o.w = f2bu(v.w);
    ((ushort4*)out)[i] = o;
}

// mean over n of img_bf; grid 256 (64 b x 1024 thread-groups of 2 cols)
__global__ __launch_bounds__(256) void mean_k(const u16* __restrict__ img_bf, float* __restrict__ gT)
{
    int id = blockIdx.x * 256 + threadIdx.x;   // 65536 = 64 b * 1024
    int b = id >> 10;
    int d = (id & 1023) * 2;
    const u16* base = img_bf + (size_t)b * 196 * 2048 + d;
    float s0 = 0.f, s1 = 0.f;
#pragma unroll 4
    for (int n = 0; n < 196; ++n) {
        ushort2 v = *(const ushort2*)(base + (size_t)n * 2048);
        s0 += b2f(v.x);
        s1 += b2f(v.y);
    }
    gT[(d + 0) * 64 + b] = s0 * (1.f / 196.f);
    gT[(d + 1) * 64 + b] = s1 * (1.f / 196.f);
}

__global__ __launch_bounds__(256) void emb_gather(const int* __restrict__ tok,
                                                  const float* __restrict__ embed,
                                                  u16* __restrict__ emb_bf)
{
    int id = blockIdx.x * 256 + threadIdx.x;
    int row = id >> 9, e = id & 511;
    int tk = tok[row];
    emb_bf[(size_t)row * 512 + e] = f2bu(embed[(size_t)tk * 512 + e]);
}

__global__ __launch_bounds__(256) void bias_sum(const float* __restrict__ a, const float* __restrict__ b,
                                                float* __restrict__ o)
{
    int i = blockIdx.x * 256 + threadIdx.x;
    o[i] = a[i] + b[i];
}

__global__ __launch_bounds__(256) void h0c0(const float* __restrict__ gT,
                                            const float* __restrict__ Wh0, const float* __restrict__ bh0,
                                            const float* __restrict__ Wc0, const float* __restrict__ bc0,
                                            float* __restrict__ c, u16* __restrict__ h0)
{
    int id = blockIdx.x * 256 + threadIdx.x;
    int b = id & 63, n = id >> 6;
    const float4* Wh = (const float4*)&Wh0[(size_t)n * 2048];
    const float4* Wc = (const float4*)&Wc0[(size_t)n * 2048];
    float s0 = 0.f, s1 = 0.f;
#pragma unroll 4
    for (int k4 = 0; k4 < 512; ++k4) {
        float4 wh = Wh[k4], wc = Wc[k4];
        float g0 = gT[(k4 * 4 + 0) * 64 + b];
        float g1 = gT[(k4 * 4 + 1) * 64 + b];
        float g2 = gT[(k4 * 4 + 2) * 64 + b];
        float g3 = gT[(k4 * 4 + 3) * 64 + b];
        s0 += wh.x * g0 + wh.y * g1 + wh.z * g2 + wh.w * g3;
        s1 += wc.x * g0 + wc.y * g1 + wc.z * g2 + wc.w * g3;
    }
    c[b * 1024 + n] = fast_tanh(s1 + bc0[n]);
    h0[(size_t)b * 1024 + n] = f2bu(fast_tanh(s0 + bh0[n]));
}

// ---------------------------------------------------------------------------
// Per-step kernels: direct global->register MFMA, no LDS staging, no K-tile
// barriers. K split across 4 waves, one LDS reduce at the end.
// ---------------------------------------------------------------------------

// ph_all[b][a] = h @ W_hid^T. grid 16 blocks x 16 a-cols.
__global__ __launch_bounds__(256) void ph_k(const u16* __restrict__ hb,      // [64][1024]
                                            const u16* __restrict__ Whid_bf, // [256][1024]
                                            float* __restrict__ ph_all)      // [64][256]
{
    const int tid = threadIdx.x, lane = tid & 63, wave = tid >> 6;
    const int fr = lane & 15, kq = (lane >> 4) * 8, rq = (lane >> 4) * 4;
    const int a0 = blockIdx.x * 16;
    __shared__ float red[4][64][16];
    f32x4 acc[4];
#pragma unroll
    for (int m = 0; m < 4; ++m) acc[m] = (f32x4){0.f, 0.f, 0.f, 0.f};
#pragma unroll
    for (int kk = 0; kk < 256; kk += 32) {
        const int k0 = wave * 256 + kk;
        bf16x8 bq = *(const bf16x8*)&Whid_bf[(size_t)(a0 + fr) * 1024 + k0 + kq];
#pragma unroll
        for (int m = 0; m < 4; ++m) {
            bf16x8 af = *(const bf16x8*)&hb[(size_t)(m * 16 + fr) * 1024 + k0 + kq];
            acc[m] = __builtin_amdgcn_mfma_f32_16x16x32_bf16(af, bq, acc[m], 0, 0, 0);
        }
    }
#pragma unroll
    for (int m = 0; m < 4; ++m)
#pragma unroll
        for (int r = 0; r < 4; ++r)
            red[wave][m * 16 + rq + r][fr] = acc[m][r];
    __syncthreads();
#pragma unroll
    for (int i = 0; i < 4; ++i) {
        const int idx = tid + i * 256;
        const int bb = idx >> 4, a = idx & 15;
        ph_all[bb * 256 + a0 + a] = red[0][bb][a] + red[1][bb][a] + red[2][bb][a] + red[3][bb][a];
    }
}

// scores + softmax + ctx quarter. grid 256 = (b, d-quarter).
__global__ __launch_bounds__(256) void attn_k(const float* __restrict__ ph_all,  // [64][256]
                                              const float* __restrict__ w_score, // [256]
                                              const float* __restrict__ proj,    // [64][196][256]
                                              const u16* __restrict__ img_bf,    // [64][196][2048]
                                              u16* __restrict__ ctx_bf)          // [64][2048]
{
    const int b = blockIdx.x >> 2, q = blockIdx.x & 3;
    const int tid = threadIdx.x, lane = tid & 63, wave = tid >> 6;
    __shared__ float ph[256], ws[256], sc[256], red[256];
    __shared__ float part[4][512];
    ph[tid] = ph_all[b * 256 + tid];
    ws[tid] = w_score[tid];
    sc[tid] = -1e30f;
    __syncthreads();
    // scores: wave w handles n = w, w+4, ...
    for (int n = wave; n < 196; n += 4) {
        const int a0 = lane * 4;
        float4 p = *(const float4*)&proj[((size_t)b * 196 + n) * 256 + a0];
        float s = ws[a0 + 0] * fast_tanh(p.x + ph[a0 + 0])
                + ws[a0 + 1] * fast_tanh(p.y + ph[a0 + 1])
                + ws[a0 + 2] * fast_tanh(p.z + ph[a0 + 2])
                + ws[a0 + 3] * fast_tanh(p.w + ph[a0 + 3]);
#pragma unroll
        for (int off = 32; off; off >>= 1) s += __shfl_xor(s, off, 64);
        if (lane == 0) sc[n] = s;
    }
    __syncthreads();
    // softmax over 196 (padded with -1e30)
    red[tid] = sc[tid];
    __syncthreads();
#pragma unroll
    for (int s2 = 128; s2 > 0; s2 >>= 1) {
        if (tid < s2) red[tid] = fmaxf(red[tid], red[tid + s2]);
        __syncthreads();
    }
    const float mx = red[0];
    __syncthreads();
    float e = (tid < 196) ? __expf(sc[tid] - mx) : 0.f;
    red[tid] = e;
    __syncthreads();
#pragma unroll
    for (int s2 = 128; s2 > 0; s2 >>= 1) {
        if (tid < s2) red[tid] += red[tid + s2];
        __syncthreads();
    }
    const float inv = __fdividef(1.f, red[0]);
    __syncthreads();
    sc[tid] = e * inv;
    __syncthreads();
    // ctx quarter: 512 cols; thread-group gid handles 8 cols, 4-way n-split
    const int gid = tid >> 2, st = tid & 3;
    const int c0 = q * 512 + gid * 8;
    const u16* base = img_bf + ((size_t)b * 196) * 2048 + c0;
    float a[8];
#pragma unroll
    for (int i = 0; i < 8; ++i) a[i] = 0.f;
    for (int n = st; n < 196; n += 4) {
        bf16x8 v = *(const bf16x8*)(base + (size_t)n * 2048);
        float wgt = sc[n];
#pragma unroll
        for (int i = 0; i < 8; ++i) a[i] += wgt * (float)v[i];
    }
#pragma unroll
    for (int i = 0; i < 8; ++i) part[st][gid * 8 + i] = a[i];
    __syncthreads();
    const int col = tid * 2;
    float v0 = part[0][col] + part[1][col] + part[2][col] + part[3][col];
    float v1 = part[0][col + 1] + part[1][col + 1] + part[2][col + 1] + part[3][col + 1];
    ushort2 o; o.x = f2bu(v0); o.y = f2bu(v1);
    *(ushort2*)&ctx_bf[(size_t)b * 2048 + q * 512 + col] = o;
}

// gates MFMA + LSTM pointwise. grid 256 blocks x 4 h-cols (x4 gates = 16 rows).
// Weight row layout for the 16-row fragment: gr = fr -> row (fr>>2)*1024 + hc0 + (fr&3).
__global__ __launch_bounds__(256) void gates_k(const u16* __restrict__ ctx_bf,  // [64][2048]
                                               const u16* __restrict__ hb,      // [64][1024] (h_t)
                                               const u16* __restrict__ Wic,     // [4096][2048]
                                               const u16* __restrict__ Whh_bf,  // [4096][1024]
                                               const float* __restrict__ xg,    // [2048][4096]
                                               float* __restrict__ cbuf,        // [64][1024]
                                               u16* __restrict__ h_nxt,         // [64][1024]
                                               u16* __restrict__ h_all,         // [2048][1024]
                                               int t)
{
    const int tid = threadIdx.x, lane = tid & 63, wave = tid >> 6;
    const int fr = lane & 15, kq = (lane >> 4) * 8, rq = (lane >> 4) * 4;
    const int hc0 = blockIdx.x * 4;
    const int grow = ((fr >> 2) << 10) + hc0 + (fr & 3);
    const u16* WicR = Wic + (size_t)grow * 2048;
    const u16* WhhR = Whh_bf + (size_t)grow * 1024;
    __shared__ float red[4][64][16];

    f32x4 acc[4];
#pragma unroll
    for (int m = 0; m < 4; ++m) acc[m] = (f32x4){0.f, 0.f, 0.f, 0.f};

    // K in [wave*768, wave*768+768): ctx region [0,2048), h region [2048,3072)
    const int kbeg = wave * 768, kend = kbeg + 768;
    const int cend = kend < 2048 ? kend : 2048;
#pragma unroll 4
    for (int k0 = kbeg; k0 < cend; k0 += 32) {
        bf16x8 bq = *(const bf16x8*)&WicR[k0 + kq];
#pragma unroll
        for (int m = 0; m < 4; ++m) {
            bf16x8 af = *(const bf16x8*)&ctx_bf[(size_t)(m * 16 + fr) * 2048 + k0 + kq];
            acc[m] = __builtin_amdgcn_mfma_f32_16x16x32_bf16(af, bq, acc[m], 0, 0, 0);
        }
    }
    const int hbeg = kbeg > 2048 ? kbeg - 2048 : 0;
    const int hend = kend > 2048 ? kend - 2048 : 0;
#pragma unroll 4
    for (int kh = hbeg; kh < hend; kh += 32) {
        bf16x8 bq = *(const bf16x8*)&WhhR[kh + kq];
#pragma unroll
        for (int m = 0; m < 4; ++m) {
            bf16x8 af = *(const bf16x8*)&hb[(size_t)(m * 16 + fr) * 1024 + kh + kq];
            acc[m] = __builtin_amdgcn_mfma_f32_16x16x32_bf16(af, bq, acc[m], 0, 0, 0);
        }
    }
#pragma unroll
    for (int m = 0; m < 4; ++m)
#pragma unroll
        for (int r = 0; r < 4; ++r)
            red[wave][m * 16 + rq + r][fr] = acc[m][r];
    __syncthreads();

    // pointwise: thread = (batch bb, col j)
    const int bb = tid >> 2, j = tid & 3;
    const int col = hc0 + j;
    float G[4];
#pragma unroll
    for (int g = 0; g < 4; ++g) {
        const int f2 = g * 4 + j;
        G[g] = red[0][bb][f2] + red[1][bb][f2] + red[2][bb][f2] + red[3][bb][f2]
             + xg[((size_t)bb * 32 + t) * 4096 + g * 1024 + col];
    }
    float ig = fast_sig(G[0]), fg = fast_sig(G[1]);
    float gv = fast_tanh(G[2]), og = fast_sig(G[3]);
    float cp = cbuf[bb * 1024 + col];
    float cn = fg * cp + ig * gv;
    cbuf[bb * 1024 + col] = cn;
    u16 hv = f2bu(og * fast_tanh(cn));
    h_nxt[(size_t)bb * 1024 + col] = hv;
    h_all[((size_t)bb * 32 + t) * 1024 + col] = hv;
}

// ---------------------------------------------------------------------------
extern "C" void kernel_launch(void* const* d_in, const int* in_sizes, int n_in,
                              void* d_out, int out_size, void* d_ws, size_t ws_size,
                              hipStream_t stream)
{
    const float* img     = (const float*)d_in[0];
    const int*   tok     = (const int*)d_in[1];
    const float* embed   = (const float*)d_in[2];
    const float* W_head1 = (const float*)d_in[3];
    const float* W_ih    = (const float*)d_in[4];
    const float* W_hh    = (const float*)d_in[5];
    const float* b_ih    = (const float*)d_in[6];
    const float* b_hh    = (const float*)d_in[7];
    const float* W_head  = (const float*)d_in[8];
    const float* W_img   = (const float*)d_in[9];
    const float* W_hid   = (const float*)d_in[10];
    const float* w_score = (const float*)d_in[11];
    const float* W_h0    = (const float*)d_in[12];
    const float* b_h0    = (const float*)d_in[13];
    const float* W_c0    = (const float*)d_in[14];
    const float* b_c0    = (const float*)d_in[15];
    float* out = (float*)d_out;

    char* w = (char*)d_ws;
    size_t off = 0;
    auto alloc = [&](size_t bytes) { char* p = w + off; off += (bytes + 255) & ~(size_t)255; return p; };

    u16*   Wic      = (u16*)alloc(4096ULL * 2048 * 2);
    u16*   Whh_bf   = (u16*)alloc(4096ULL * 1024 * 2);
    u16*   Whid_bf  = (u16*)alloc(256ULL * 1024 * 2);
    u16*   Whead_bf = (u16*)alloc(32000ULL * 1024 * 2);
    u16*   img_bf   = (u16*)alloc(64ULL * 196 * 2048 * 2);
    float* xg       = (float*)alloc(2048ULL * 4096 * 4);
    float* proj     = (float*)alloc(64ULL * 196 * 256 * 4);
    u16*   emb_bf   = (u16*)alloc(2048ULL * 512 * 2);
    u16*   xe       = (u16*)alloc(2048ULL * 512 * 2);
    float* gT       = (float*)alloc(2048ULL * 64 * 4);
    float* cbuf     = (float*)alloc(64ULL * 1024 * 4);
    u16*   hbuf     = (u16*)alloc(2ULL * 64 * 1024 * 2);
    u16*   ctx_bf   = (u16*)alloc(64ULL * 2048 * 2);
    u16*   h_all    = (u16*)alloc(2048ULL * 1024 * 2);
    float* ph_all   = (float*)alloc(64ULL * 256 * 4);
    float* bsum     = (float*)alloc(4096ULL * 4);
    (void)ws_size; (void)in_sizes; (void)n_in; (void)out_size;

    // ---- prologue
    cvt_bf16<<<dim3(25088), dim3(256), 0, stream>>>(img, img_bf);
    cvt_bf16<<<dim3(4096), dim3(256), 0, stream>>>(W_hh, Whh_bf);
    cvt_bf16<<<dim3(256), dim3(256), 0, stream>>>(W_hid, Whid_bf);
    cvt_bf16<<<dim3(32000), dim3(256), 0, stream>>>(W_head, Whead_bf);
    mean_k<<<dim3(256), dim3(256), 0, stream>>>(img_bf, gT);
    emb_gather<<<dim3(4096), dim3(256), 0, stream>>>(tok, embed, emb_bf);
    bias_sum<<<dim3(16), dim3(256), 0, stream>>>(b_ih, b_hh, bsum);
    h0c0<<<dim3(256), dim3(256), 0, stream>>>(gT, W_h0, b_h0, W_c0, b_c0, cbuf, hbuf);

    // xe = emb @ Wa^T (Wa = W_head1[:, :512])
    gemm128<false, true, false, true, false><<<dim3(4, 16), dim3(256), 0, stream>>>(
        emb_bf, 512, W_head1, 2560, xe, 512, nullptr, 512);
    // xg = xe @ W_ih^T + (b_ih + b_hh)
    gemm128<false, true, false, false, true><<<dim3(32, 16), dim3(256), 0, stream>>>(
        xe, 512, W_ih, 512, xg, 4096, bsum, 512);
    // Wic = W_ih @ W_head1[:, 512:]
    gemm128<true, true, true, true, false><<<dim3(16, 32), dim3(256), 0, stream>>>(
        W_ih, 512, W_head1 + 512, 2560, Wic, 2048, nullptr, 512);
    // proj = img_bf @ W_img^T
    gemm128<false, true, false, false, false><<<dim3(2, 98), dim3(256), 0, stream>>>(
        img_bf, 2048, W_img, 2048, proj, 256, nullptr, 2048);

    // ---- recurrence: 3 small latency-tolerant kernels per step
    for (int t = 0; t < 32; ++t) {
        u16* hb = hbuf + (size_t)(t & 1) * 65536;
        u16* hn = hbuf + (size_t)((t + 1) & 1) * 65536;
        ph_k<<<dim3(16), dim3(256), 0, stream>>>(hb, Whid_bf, ph_all);
        attn_k<<<dim3(256), dim3(256), 0, stream>>>(ph_all, w_score, proj, img_bf, ctx_bf);
        gates_k<<<dim3(256), dim3(256), 0, stream>>>(ctx_bf, hb, Wic, Whh_bf, xg,
                                                     cbuf, hn, h_all, t);
    }

    // ---- logits: out = h_all @ W_head^T
    gemm_head<<<dim3(4000), dim3(256), 0, stream>>>(h_all, Whead_bf, out);
}